// Round 1
// baseline (29757.639 us; speedup 1.0000x reference)
//
#include <hip/hip_runtime.h>
#include <math.h>

#define T_STEPS 512
#define BATCH   64
#define ISIZE   512
#define HSIZE   512
#define GSIZE   2048   // 4*H
#define KSIZE   1024   // I + H

// ---------------------------------------------------------------------------
// Pack [wih; whh] into wPK[col][k], k-major per column, with the column
// permutation  col = hsb*64 + gate*16 + hj  <->  g = gate*512 + hsb*16 + hj
// so that one block (h-slice hsb) owns 64 contiguous columns covering all
// 4 gates of its 16 h-indices.
// ---------------------------------------------------------------------------
__global__ void pack_weights(const float* __restrict__ wih,
                             const float* __restrict__ whh,
                             float* __restrict__ wPK) {
    int idx = blockIdx.x * blockDim.x + threadIdx.x;   // [0, GSIZE*KSIZE)
    if (idx >= GSIZE * KSIZE) return;
    int col = idx >> 10;        // [0,2048)
    int k   = idx & 1023;       // [0,1024)
    int w    = col & 63;
    int hsb  = col >> 6;
    int gate = w >> 4;
    int hj   = w & 15;
    int g = gate * HSIZE + hsb * 16 + hj;
    float v = (k < ISIZE) ? wih[(size_t)g * ISIZE + k]
                          : whh[(size_t)g * HSIZE + (k - ISIZE)];
    wPK[idx] = v;   // wPK[col*KSIZE + k], coalesced write
}

__global__ void init_state(const float* __restrict__ hx,
                           const float* __restrict__ cx,
                           const float* __restrict__ bih,
                           const float* __restrict__ bhh,
                           float* __restrict__ hbuf0,
                           float* __restrict__ cbuf,
                           float* __restrict__ bias2) {
    int idx = blockIdx.x * blockDim.x + threadIdx.x;
    if (idx < BATCH * HSIZE) {
        hbuf0[idx] = hx[idx];
        cbuf[idx]  = cx[idx];
    }
    if (idx < GSIZE) {
        int w = idx & 63, hsb = idx >> 6;
        int g = (w >> 4) * HSIZE + hsb * 16 + (w & 15);
        bias2[idx] = bih[g] + bhh[g];
    }
}

// ---------------------------------------------------------------------------
// One LSTM timestep. grid = (32 h-slices, 8 batch-groups), block = 512.
// Each block: 8 batch rows x 64 gate-columns (4 gates x 16 h).
// Each thread: one gate value = K=1024 dot product, float4 streaming.
// ---------------------------------------------------------------------------
__global__ __launch_bounds__(512) void lstm_step(
    const float* __restrict__ x_t,     // [BATCH][ISIZE] slice for this t
    const float* __restrict__ wPK,     // [GSIZE][KSIZE] packed
    const float* __restrict__ bias2,   // [GSIZE] packed
    const float* __restrict__ h_prev,  // [BATCH][HSIZE]
    float* __restrict__ h_next,        // [BATCH][HSIZE]
    float* __restrict__ c)             // [BATCH][HSIZE] in-place
{
    __shared__ float xs [8 * ISIZE];   // 16 KB
    __shared__ float hsm[8 * HSIZE];   // 16 KB
    __shared__ float gbuf[8][64];      // 2 KB

    const int tid   = threadIdx.x;
    const int hsb   = blockIdx.x;      // [0,32)
    const int bg    = blockIdx.y;      // [0,8)
    const int bbase = bg * 8;

    // cooperative load: 8 contiguous batch rows of x_t and h_prev
    const float4* xsrc = reinterpret_cast<const float4*>(x_t    + (size_t)bbase * ISIZE);
    const float4* hsrc = reinterpret_cast<const float4*>(h_prev + (size_t)bbase * HSIZE);
    float4* xdst = reinterpret_cast<float4*>(xs);
    float4* hdst = reinterpret_cast<float4*>(hsm);
    #pragma unroll
    for (int i = tid; i < 8 * ISIZE / 4; i += 512) {
        xdst[i] = xsrc[i];
        hdst[i] = hsrc[i];
    }
    __syncthreads();

    const int col  = tid & 63;
    const int b    = tid >> 6;          // [0,8)
    const int gcol = hsb * 64 + col;

    const float4* wp = reinterpret_cast<const float4*>(wPK + (size_t)gcol * KSIZE);
    const float4* xr = reinterpret_cast<const float4*>(xs  + b * ISIZE);
    const float4* hr = reinterpret_cast<const float4*>(hsm + b * HSIZE);

    float acc = bias2[gcol];
    #pragma unroll 8
    for (int k4 = 0; k4 < ISIZE / 4; ++k4) {
        float4 w4 = wp[k4];
        float4 v4 = xr[k4];
        acc += w4.x * v4.x + w4.y * v4.y + w4.z * v4.z + w4.w * v4.w;
    }
    #pragma unroll 8
    for (int k4 = 0; k4 < HSIZE / 4; ++k4) {
        float4 w4 = wp[ISIZE / 4 + k4];
        float4 v4 = hr[k4];
        acc += w4.x * v4.x + w4.y * v4.y + w4.z * v4.z + w4.w * v4.w;
    }
    gbuf[b][col] = acc;
    __syncthreads();

    // pointwise LSTM cell update: 128 threads = 8 batch rows x 16 h
    if (tid < 128) {
        int hj = tid & 15;
        int br = tid >> 4;
        float ig = gbuf[br][ 0 + hj];
        float fg = gbuf[br][16 + hj];
        float gg = gbuf[br][32 + hj];
        float og = gbuf[br][48 + hj];
        ig = 1.f / (1.f + __expf(-ig));
        fg = 1.f / (1.f + __expf(-fg));
        og = 1.f / (1.f + __expf(-og));
        gg = tanhf(gg);
        int hidx = hsb * 16 + hj;
        size_t ci = (size_t)(bbase + br) * HSIZE + hidx;
        float cn = fg * c[ci] + ig * gg;
        c[ci] = cn;
        h_next[ci] = og * tanhf(cn);
    }
}

__global__ void epilogue(const float* __restrict__ hfin,
                         const float* __restrict__ cfin,
                         float* __restrict__ out) {
    int i = blockIdx.x * blockDim.x + threadIdx.x;  // float4 index, 16384 total
    const int NH4 = BATCH * HSIZE / 4;              // 8192
    float4* o = reinterpret_cast<float4*>(out);
    if (i < NH4) {
        o[i] = reinterpret_cast<const float4*>(hfin)[i];
    } else if (i < 2 * NH4) {
        o[i] = reinterpret_cast<const float4*>(cfin)[i - NH4];
    }
}

extern "C" void kernel_launch(void* const* d_in, const int* in_sizes, int n_in,
                              void* d_out, int out_size, void* d_ws, size_t ws_size,
                              hipStream_t stream) {
    const float* input = (const float*)d_in[0];  // [T][B][I]
    const float* hx    = (const float*)d_in[1];  // [B][H]
    const float* cx    = (const float*)d_in[2];  // [B][H]
    const float* wih   = (const float*)d_in[3];  // [4H][I]
    const float* whh   = (const float*)d_in[4];  // [4H][H]
    const float* bih   = (const float*)d_in[5];  // [4H]
    const float* bhh   = (const float*)d_in[6];  // [4H]
    float* out = (float*)d_out;

    char* ws = (char*)d_ws;
    float* wPK   = (float*)(ws);                       // 8 MB
    float* bias2 = (float*)(ws + 8388608);             // 8 KB
    float* hbuf0 = (float*)(ws + 8396800);             // 128 KB
    float* hbuf1 = (float*)(ws + 8527872);             // 128 KB
    float* cbuf  = (float*)(ws + 8658944);             // 128 KB
    // total ~8.8 MB of ws used

    pack_weights<<<GSIZE * KSIZE / 256, 256, 0, stream>>>(wih, whh, wPK);
    init_state<<<BATCH * HSIZE / 256, 256, 0, stream>>>(hx, cx, bih, bhh,
                                                        hbuf0, cbuf, bias2);

    dim3 grid(32, 8);
    float* hb[2] = {hbuf0, hbuf1};
    for (int t = 0; t < T_STEPS; ++t) {
        lstm_step<<<grid, 512, 0, stream>>>(
            input + (size_t)t * BATCH * ISIZE,
            wPK, bias2, hb[t & 1], hb[(t + 1) & 1], cbuf);
    }
    // after t=511, final h is in hbuf0 (512 is even), c in cbuf
    epilogue<<<64, 256, 0, stream>>>(hbuf0, cbuf, out);
}

// Round 2
// 3100.020 us; speedup vs baseline: 9.5992x; 9.5992x over previous
//
#include <hip/hip_runtime.h>
#include <math.h>

#define TSTEPS 512
#define B      64
#define I      512
#define H      512
#define G      2048   // 4*H
#define K      1024   // I + H
#define KT     256    // K-tile staged in LDS
#define LDP    264    // padded LDS row stride (bf16 elems): 528B -> 2-way bank alias (free)

typedef __attribute__((ext_vector_type(8))) short          short8;  // 8 bf16 = 4 VGPRs (MFMA frag)
typedef __attribute__((ext_vector_type(8))) unsigned short u16x8;
typedef __attribute__((ext_vector_type(4))) float          f32x4;

__device__ __forceinline__ unsigned short f2bf(float f) {
    union { float f; unsigned int u; } v; v.f = f;
    unsigned int r = v.u + 0x7fffu + ((v.u >> 16) & 1u);   // RNE
    return (unsigned short)(r >> 16);
}
__device__ __forceinline__ float bf2f(unsigned short b) {
    union { unsigned int u; float f; } v; v.u = ((unsigned int)b) << 16;
    return v.f;
}

// ---------------------------------------------------------------------------
// Pack [wih; whh] -> bf16 wbf[col][k], k-contiguous per column ("B^T" layout).
// Column permutation: col = hsb*32 + gate*8 + hj  <->  g = gate*H + hsb*8 + hj
// so block nb owns 32 contiguous cols = all 4 gates of its 8 h-indices.
// ---------------------------------------------------------------------------
__global__ void pack_w(const float* __restrict__ wih,
                       const float* __restrict__ whh,
                       unsigned short* __restrict__ wbf) {
    int idx = blockIdx.x * 256 + threadIdx.x;   // [0, G*K/4)
    int col = idx >> 8;                         // [0,2048)
    int k0  = (idx & 255) << 2;                 // [0,1024) step 4
    int w = col & 31, hsb = col >> 5;
    int g = (w >> 3) * H + hsb * 8 + (w & 7);
    float4 v = (k0 < I) ? *(const float4*)(wih + (size_t)g * I + k0)
                        : *(const float4*)(whh + (size_t)g * H + (k0 - I));
    ushort4 o = { f2bf(v.x), f2bf(v.y), f2bf(v.z), f2bf(v.w) };
    *(ushort4*)(wbf + (size_t)col * K + k0) = o;
}

__global__ void init_state(const float* __restrict__ hx,
                           const float* __restrict__ cx,
                           const float* __restrict__ bih,
                           const float* __restrict__ bhh,
                           unsigned short* __restrict__ hbf0,
                           float* __restrict__ cbuf,
                           float* __restrict__ bias2) {
    int i = blockIdx.x * 256 + threadIdx.x;
    if (i < B * H) { hbf0[i] = f2bf(hx[i]); cbuf[i] = cx[i]; }
    if (i < G) {
        int w = i & 31, hsb = i >> 5;
        int g = (w >> 3) * H + hsb * 8 + (w & 7);
        bias2[i] = bih[g] + bhh[g];
    }
}

// ---------------------------------------------------------------------------
// One LSTM step. grid = (2 row-groups, 64 col-strips), block = 256 (4 waves).
// Block (mg, nb): batch rows mg*32..+32, packed gate-cols nb*32..+32
// (= all 4 gates of h-indices nb*8..+8). MFMA 16x16x32 bf16, fused cell update.
// ---------------------------------------------------------------------------
__global__ __launch_bounds__(256) void lstm_step(
    const float* __restrict__ x_t,              // [B][I] fp32
    const unsigned short* __restrict__ wbf,     // [G][K] bf16 packed
    const float* __restrict__ bias2,            // [G] packed
    const unsigned short* __restrict__ h_prev,  // [B][H] bf16
    unsigned short* __restrict__ h_next,        // [B][H] bf16
    float* __restrict__ c)                      // [B][H] fp32 in-place
{
    __shared__ unsigned short xs [32 * LDP];    // 16.5 KB  X tile (32 rows x 256 k)
    __shared__ unsigned short wsm[32 * LDP];    // 16.5 KB  W tile (32 cols x 256 k)
    __shared__ float gbuf[32][33];              // 4.2 KB   gate values

    const int tid  = threadIdx.x;
    const int mg   = blockIdx.x;                // [0,2)
    const int nb   = blockIdx.y;                // [0,64)
    const int lane = tid & 63;
    const int wv   = tid >> 6;                  // wave [0,4)

    const int rbase = mg * 32;                  // batch-row base
    const int cbase = nb * 32;                  // packed-col base

    // MFMA fragment addressing: A[row][k0..k0+8], B^T[col][k0..k0+8]
    const int fr = lane & 15;
    const int fk = (lane >> 4) * 8;

    // staging map: 8 threads per row/col, 16B chunks interleaved (conflict-free)
    const int sr = tid >> 3;                    // [0,32)
    const int sc = (tid & 7) * 8;               // elem offset, +64 per j

    f32x4 accA = {0.f,0.f,0.f,0.f}, accB = {0.f,0.f,0.f,0.f};

    for (int kt = 0; kt < K; kt += KT) {
        // ---- stage X tile (convert fp32 x_t, or copy bf16 h_prev) ----
        if (kt < I) {
            const float* src = x_t + (size_t)(rbase + sr) * I + kt;
            unsigned short* dst = xs + sr * LDP;
            #pragma unroll
            for (int j = 0; j < 4; ++j) {
                int k = sc + j * 64;
                float4 a = *(const float4*)(src + k);
                float4 b = *(const float4*)(src + k + 4);
                u16x8 o;
                o[0]=f2bf(a.x); o[1]=f2bf(a.y); o[2]=f2bf(a.z); o[3]=f2bf(a.w);
                o[4]=f2bf(b.x); o[5]=f2bf(b.y); o[6]=f2bf(b.z); o[7]=f2bf(b.w);
                *(u16x8*)(dst + k) = o;
            }
        } else {
            const unsigned short* src = h_prev + (size_t)(rbase + sr) * H + (kt - I);
            unsigned short* dst = xs + sr * LDP;
            #pragma unroll
            for (int j = 0; j < 4; ++j) {
                int k = sc + j * 64;
                *(u16x8*)(dst + k) = *(const u16x8*)(src + k);
            }
        }
        // ---- stage W tile ----
        {
            const unsigned short* src = wbf + (size_t)(cbase + sr) * K + kt;
            unsigned short* dst = wsm + sr * LDP;
            #pragma unroll
            for (int j = 0; j < 4; ++j) {
                int k = sc + j * 64;
                *(u16x8*)(dst + k) = *(const u16x8*)(src + k);
            }
        }
        __syncthreads();

        // ---- MFMA: wave -> rows (wv&1)*16, cols (wv>>1)*16 ----
        const unsigned short* ap = xs  + ((wv & 1) * 16 + fr) * LDP + fk;
        const unsigned short* bp = wsm + ((wv >> 1) * 16 + fr) * LDP + fk;
        #pragma unroll
        for (int ks = 0; ks < KT / 32; ++ks) {   // 8
            short8 af = *(const short8*)(ap + ks * 32);
            short8 bf = *(const short8*)(bp + ks * 32);
            if (ks & 1) accB = __builtin_amdgcn_mfma_f32_16x16x32_bf16(af, bf, accB, 0, 0, 0);
            else        accA = __builtin_amdgcn_mfma_f32_16x16x32_bf16(af, bf, accA, 0, 0, 0);
        }
        __syncthreads();
    }

    // ---- C layout: col = lane&15, row = (lane>>4)*4 + e  (m89-verified) ----
    #pragma unroll
    for (int e = 0; e < 4; ++e) {
        int r  = (wv & 1) * 16 + (lane >> 4) * 4 + e;
        int cc = (wv >> 1) * 16 + fr;
        gbuf[r][cc] = accA[e] + accB[e];
    }
    __syncthreads();

    // ---- fused LSTM cell update: thread -> (batch row, h index) ----
    {
        int br = tid >> 3;      // [0,32) local batch row
        int hj = tid & 7;       // [0,8)  local h index
        float ig = gbuf[br][ 0 + hj] + bias2[cbase +  0 + hj];
        float fg = gbuf[br][ 8 + hj] + bias2[cbase +  8 + hj];
        float gg = gbuf[br][16 + hj] + bias2[cbase + 16 + hj];
        float og = gbuf[br][24 + hj] + bias2[cbase + 24 + hj];
        ig = 1.f / (1.f + __expf(-ig));
        fg = 1.f / (1.f + __expf(-fg));
        og = 1.f / (1.f + __expf(-og));
        gg = tanhf(gg);
        size_t ci = (size_t)(rbase + br) * H + nb * 8 + hj;
        float cn = fg * c[ci] + ig * gg;
        c[ci] = cn;
        h_next[ci] = f2bf(og * tanhf(cn));
    }
}

__global__ void epilogue(const unsigned short* __restrict__ hbf,
                         const float* __restrict__ cfin,
                         float* __restrict__ out) {
    int i = blockIdx.x * 256 + threadIdx.x;
    if (i < B * H) {
        out[i] = bf2f(hbf[i]);
        out[B * H + i] = cfin[i];
    }
}

extern "C" void kernel_launch(void* const* d_in, const int* in_sizes, int n_in,
                              void* d_out, int out_size, void* d_ws, size_t ws_size,
                              hipStream_t stream) {
    const float* input = (const float*)d_in[0];  // [T][B][I]
    const float* hx    = (const float*)d_in[1];
    const float* cx    = (const float*)d_in[2];
    const float* wih   = (const float*)d_in[3];
    const float* whh   = (const float*)d_in[4];
    const float* bih   = (const float*)d_in[5];
    const float* bhh   = (const float*)d_in[6];
    float* out = (float*)d_out;

    char* ws = (char*)d_ws;
    unsigned short* wbf   = (unsigned short*)(ws);                  // 4 MB
    float*          bias2 = (float*)(ws + 4194304);                 // 8 KB
    float*          cbuf  = (float*)(ws + 4194304 + 8192);          // 128 KB
    unsigned short* hbf0  = (unsigned short*)(ws + 4333568);        // 64 KB
    unsigned short* hbf1  = (unsigned short*)(ws + 4399104);        // 64 KB
    // total ws used: ~4.46 MB

    pack_w<<<G * K / 4 / 256, 256, 0, stream>>>(wih, whh, wbf);
    init_state<<<B * H / 256, 256, 0, stream>>>(hx, cx, bih, bhh, hbf0, cbuf, bias2);

    dim3 grid(2, 64);
    for (int t = 0; t < TSTEPS; ++t) {
        lstm_step<<<grid, 256, 0, stream>>>(
            input + (size_t)t * B * I, wbf, bias2,
            (t & 1) ? hbf1 : hbf0,
            (t & 1) ? hbf0 : hbf1,
            cbuf);
    }
    // TSTEPS even -> final h in hbf0
    epilogue<<<B * H / 256, 256, 0, stream>>>(hbf0, cbuf, out);
}